// Round 1
// baseline (390.261 us; speedup 1.0000x reference)
//
#include <hip/hip_runtime.h>
#include <string.h>

#define OUT_DIM 11008
#define IN_DIM  4096
#define NTOK    64
#define RANK    128
#define NG      32

typedef float        v4f  __attribute__((ext_vector_type(4)));
typedef int          v4i  __attribute__((ext_vector_type(4)));
typedef unsigned int v4u  __attribute__((ext_vector_type(4)));
typedef _Float16     v8h  __attribute__((ext_vector_type(8)));

// ---------------- K0: pack svd_down (f32 [128][4096]) into f16 row-pairs ----------------
// dp[r2*4096 + c] = { D[2*r2][c] (lo), D[2*r2+1][c] (hi) }  — matches the f16 MFMA
// B-fragment register layout (k ascending within dword).
__device__ inline unsigned int pack2h(float lo, float hi) {
  union { _Float16 h[2]; unsigned int u; } t;
  t.h[0] = (_Float16)lo; t.h[1] = (_Float16)hi;
  return t.u;
}

__global__ __launch_bounds__(256) void pack_d_kernel(const float* __restrict__ d,
                                                     unsigned int* __restrict__ dp) {
  int idx = (blockIdx.x * 256 + threadIdx.x) * 4;   // dword index
  int r2 = idx >> 12, c = idx & 4095;
  v4f a = *(const v4f*)(d + (2 * r2) * IN_DIM + c);
  v4f b = *(const v4f*)(d + (2 * r2 + 1) * IN_DIM + c);
  v4u o;
#pragma unroll
  for (int e = 0; e < 4; e++) o[e] = pack2h(a[e], b[e]);
  *(v4u*)(dp + idx) = o;
}

// ---------------- K1: dynamic-quantize x per token ----------------
__global__ __launch_bounds__(256) void quant_x_kernel(const float* __restrict__ x,
                                                      signed char* __restrict__ xq,
                                                      float* __restrict__ sx) {
  int t = blockIdx.x, tid = threadIdx.x;
  const float* row = x + t * IN_DIM;
  v4f v[4];
  float m = 0.f;
#pragma unroll
  for (int i = 0; i < 4; i++) {
    v[i] = *(const v4f*)(row + tid * 16 + i * 4);
#pragma unroll
    for (int e = 0; e < 4; e++) m = fmaxf(m, fabsf(v[i][e]));
  }
#pragma unroll
  for (int off = 1; off < 64; off <<= 1) m = fmaxf(m, __shfl_xor(m, off));
  __shared__ float wm[4];
  if ((tid & 63) == 0) wm[tid >> 6] = m;
  __syncthreads();
  m = fmaxf(fmaxf(wm[0], wm[1]), fmaxf(wm[2], wm[3]));
  float s = m / 127.0f;                      // exactly ref: max/127
  if (tid == 0) sx[t] = s;
  unsigned int packed[4];
#pragma unroll
  for (int i = 0; i < 4; i++) {
    int q[4];
#pragma unroll
    for (int e = 0; e < 4; e++) {
      float qf = rintf(v[i][e] / s);         // half-even like jnp.round
      qf = fminf(127.f, fmaxf(-128.f, qf));
      q[e] = (int)qf;
    }
    packed[i] = (q[0] & 255) | ((q[1] & 255) << 8) | ((q[2] & 255) << 16) | ((q[3] & 255) << 24);
  }
  *(v4u*)(xq + t * IN_DIM + tid * 16) = *(v4u*)packed;
}

// ---------------- shared device helpers for the two weight-pass kernels ----------------
__device__ inline void load_u(const float* __restrict__ svd_up, _Float16 (*U)[136],
                              int tid, int r0) {
#pragma unroll
  for (int i = 0; i < 16; i++) {
    int idx = i * 256 + tid;
    int r = idx >> 7, k = idx & 127;
    U[r][k] = (_Float16)svd_up[(r0 + r) * RANK + k];
  }
}

__device__ inline void stage_d(const unsigned int* __restrict__ dp, unsigned int (*Dl)[128],
                               int tid, int kt) {
  int c = (tid & 31) * 4;
#pragma unroll
  for (int i = 0; i < 8; i++) {
    int r2 = i * 8 + (tid >> 5);
    *(v4u*)&Dl[r2][c] = *(const v4u*)(dp + r2 * IN_DIM + kt * 128 + c);
  }
}

// C-tile [32 rows][128 cols] = U_tile[32][128] @ D_slice[128][128], f16 MFMA 16x16x32.
// Wave w owns cols [w*32, w*32+32); fm in {0,1} row-frags, fn in {0,1} col-frags.
__device__ inline void svd_mfma(const _Float16 (*U)[136], const unsigned int (*Dl)[128],
                                int l, int w, v4f acc[2][2]) {
#pragma unroll
  for (int ks = 0; ks < 4; ks++) {
    v8h a0 = *(const v8h*)&U[(l & 15)][ks * 32 + (l >> 4) * 8];
    v8h a1 = *(const v8h*)&U[16 + (l & 15)][ks * 32 + (l >> 4) * 8];
#pragma unroll
    for (int fn = 0; fn < 2; fn++) {
      int col = w * 32 + fn * 16 + (l & 15);
      int rb = ks * 16 + (l >> 4) * 4;
      union { unsigned int u[4]; v8h h; } bu;
      bu.u[0] = Dl[rb][col];
      bu.u[1] = Dl[rb + 1][col];
      bu.u[2] = Dl[rb + 2][col];
      bu.u[3] = Dl[rb + 3][col];
      acc[0][fn] = __builtin_amdgcn_mfma_f32_16x16x32_f16(a0, bu.h, acc[0][fn], 0, 0, 0);
      acc[1][fn] = __builtin_amdgcn_mfma_f32_16x16x32_f16(a1, bu.h, acc[1][fn], 0, 0, 0);
    }
  }
}

// ---------------- K2: per-row max |W_f| -> scale_w ----------------
__global__ __launch_bounds__(256, 2) void rowmax_kernel(const int* __restrict__ wq,
    const float* __restrict__ scale, const float* __restrict__ zp,
    const float* __restrict__ svd_up, const unsigned int* __restrict__ dp,
    float* __restrict__ sw) {
  __shared__ _Float16 U[32][136];
  __shared__ unsigned int Dl[64][128];
  __shared__ float Cl[32][132];
  int tid = threadIdx.x;
  int r0 = blockIdx.x * 32;
  load_u(svd_up, U, tid, r0);
  int l = tid & 63, w = tid >> 6;
  int myrow = tid >> 3, c0 = (tid & 7) * 16;   // each thread owns 1 row x 16 cols per tile
  float rmax = 0.f;
  __syncthreads();
  for (int kt = 0; kt < 32; kt++) {
    stage_d(dp, Dl, tid, kt);
    __syncthreads();
    v4f acc[2][2] = {};
    svd_mfma(U, Dl, l, w, acc);
#pragma unroll
    for (int fm = 0; fm < 2; fm++)
#pragma unroll
      for (int fn = 0; fn < 2; fn++)
#pragma unroll
        for (int j = 0; j < 4; j++)
          Cl[fm * 16 + (l >> 4) * 4 + j][w * 32 + fn * 16 + (l & 15)] = acc[fm][fn][j];
    __syncthreads();
    float s = scale[(r0 + myrow) * NG + kt];   // KT=128 == group size: one group per tile
    float z = zp[(r0 + myrow) * NG + kt];
    const v4i* wp = (const v4i*)(wq + (r0 + myrow) * IN_DIM + kt * 128 + c0);
#pragma unroll
    for (int i = 0; i < 4; i++) {
      v4i wv = wp[i];
      v4f cv = *(const v4f*)&Cl[myrow][c0 + i * 4];
#pragma unroll
      for (int e = 0; e < 4; e++) {
        float W = ((float)wv[e] - z) * s + cv[e];
        rmax = fmaxf(rmax, fabsf(W));
      }
    }
    __syncthreads();
  }
  rmax = fmaxf(rmax, __shfl_xor(rmax, 1));
  rmax = fmaxf(rmax, __shfl_xor(rmax, 2));
  rmax = fmaxf(rmax, __shfl_xor(rmax, 4));
  if ((tid & 7) == 0) sw[r0 + myrow] = rmax / 127.0f;
}

// ---------------- K3: quantize W + int8 matmul + epilogue ----------------
__global__ __launch_bounds__(256, 2) void matmul_kernel(const int* __restrict__ wq,
    const float* __restrict__ scale, const float* __restrict__ zp,
    const float* __restrict__ svd_up, const unsigned int* __restrict__ dp,
    const signed char* __restrict__ xq, const float* __restrict__ sx,
    const float* __restrict__ sw, const float* __restrict__ bias,
    float* __restrict__ out) {
  __shared__ _Float16 U[32][136];
  __shared__ unsigned int Dl[64][128];
  __shared__ float Cl[32][132];
  __shared__ unsigned int W8[32][33];   // 33-dword stride: conflict-friendly b32 reads
  __shared__ float sxl[64];
  int tid = threadIdx.x;
  int r0 = blockIdx.x * 32;
  load_u(svd_up, U, tid, r0);
  if (tid < 64) sxl[tid] = sx[tid];
  int l = tid & 63, w = tid >> 6;
  int myrow = tid >> 3, c0 = (tid & 7) * 16;
  float swr = sw[r0 + myrow];
  v4i oacc[2] = {};
  __syncthreads();
  for (int kt = 0; kt < 32; kt++) {
    stage_d(dp, Dl, tid, kt);
    __syncthreads();
    v4f acc[2][2] = {};
    svd_mfma(U, Dl, l, w, acc);       // identical code to rowmax pass -> same W bits
#pragma unroll
    for (int fm = 0; fm < 2; fm++)
#pragma unroll
      for (int fn = 0; fn < 2; fn++)
#pragma unroll
        for (int j = 0; j < 4; j++)
          Cl[fm * 16 + (l >> 4) * 4 + j][w * 32 + fn * 16 + (l & 15)] = acc[fm][fn][j];
    __syncthreads();
    float s = scale[(r0 + myrow) * NG + kt];
    float z = zp[(r0 + myrow) * NG + kt];
    const v4i* wp = (const v4i*)(wq + (r0 + myrow) * IN_DIM + kt * 128 + c0);
#pragma unroll
    for (int i = 0; i < 4; i++) {
      v4i wv = wp[i];
      v4f cv = *(const v4f*)&Cl[myrow][c0 + i * 4];
      int q[4];
#pragma unroll
      for (int e = 0; e < 4; e++) {
        float W = ((float)wv[e] - z) * s + cv[e];
        float qf = rintf(W / swr);
        qf = fminf(127.f, fmaxf(-128.f, qf));
        q[e] = (int)qf;
      }
      W8[myrow][(c0 >> 2) + i] =
          (q[0] & 255) | ((q[1] & 255) << 8) | ((q[2] & 255) << 16) | ((q[3] & 255) << 24);
    }
    __syncthreads();
    // int8 matmul: wave w owns tokens [w*16, w*16+16); fr in {0,1} row-frags of 16
#pragma unroll
    for (int ks = 0; ks < 2; ks++) {
      v4i a = *(const v4i*)(xq + (w * 16 + (l & 15)) * IN_DIM + kt * 128 + ks * 64 + (l >> 4) * 16);
#pragma unroll
      for (int fr = 0; fr < 2; fr++) {
        int rr = fr * 16 + (l & 15);
        int kd = ks * 16 + (l >> 4) * 4;
        v4i b;
        b[0] = (int)W8[rr][kd];
        b[1] = (int)W8[rr][kd + 1];
        b[2] = (int)W8[rr][kd + 2];
        b[3] = (int)W8[rr][kd + 3];
        oacc[fr] = __builtin_amdgcn_mfma_i32_16x16x64_i8(a, b, oacc[fr], 0, 0, 0);
      }
    }
  }
  // epilogue: out[t,o] = acc * sx[t] * sw[o] + bias[o]
#pragma unroll
  for (int fr = 0; fr < 2; fr++) {
#pragma unroll
    for (int j = 0; j < 4; j++) {
      int token = w * 16 + (l >> 4) * 4 + j;
      int orow = r0 + fr * 16 + (l & 15);
      float v = (float)oacc[fr][j] * sxl[token] * sw[orow] + bias[orow];
      out[token * OUT_DIM + orow] = v;
    }
  }
}

// ---------------- launch ----------------
extern "C" void kernel_launch(void* const* d_in, const int* in_sizes, int n_in,
                              void* d_out, int out_size, void* d_ws, size_t ws_size,
                              hipStream_t stream) {
  (void)in_sizes; (void)n_in; (void)out_size; (void)ws_size;
  const float* x        = (const float*)d_in[0];
  const int*   wq       = (const int*)d_in[1];
  const float* scale    = (const float*)d_in[2];
  const float* zp       = (const float*)d_in[3];
  const float* svd_up   = (const float*)d_in[4];
  const float* svd_down = (const float*)d_in[5];
  const float* bias     = (const float*)d_in[6];
  float* out = (float*)d_out;

  char* ws = (char*)d_ws;
  unsigned int* dp = (unsigned int*)ws;                       // 1,048,576 B : f16-paired svd_down
  signed char*  xq = (signed char*)(ws + 1048576);            //   262,144 B : x int8
  float*        sx = (float*)(ws + 1048576 + 262144);         //       256 B : scale_x
  float*        sw = (float*)(ws + 1048576 + 262144 + 256);   //    44,032 B : scale_w

  pack_d_kernel<<<256, 256, 0, stream>>>(svd_down, dp);
  quant_x_kernel<<<NTOK, 256, 0, stream>>>(x, xq, sx);
  rowmax_kernel<<<OUT_DIM / 32, 256, 0, stream>>>(wq, scale, zp, svd_up, dp, sw);
  matmul_kernel<<<OUT_DIM / 32, 256, 0, stream>>>(wq, scale, zp, svd_up, dp, xq, sx, sw, bias, out);
}